// Round 25
// baseline (88.978 us; speedup 1.0000x reference)
//
#include <hip/hip_runtime.h>
#include <hip/hip_bf16.h>

typedef __bf16 bf16x8 __attribute__((ext_vector_type(8)));
typedef float f32x4 __attribute__((ext_vector_type(4)));
typedef float f32x16 __attribute__((ext_vector_type(16)));

__device__ inline unsigned short f2bf(float f) {
    __hip_bfloat16 h = __float2bfloat16(f);
    return __builtin_bit_cast(unsigned short, h);
}
// packed RNE f32->bf16 convert (HW op, single instruction): dst = {bf16(a), bf16(b)}
__device__ inline unsigned cvtpk(float a, float b) {
    unsigned r;
    asm("v_cvt_pk_bf16_f32 %0, %1, %2" : "=v"(r) : "v"(a), "v"(b));
    return r;
}
// truncation-pack: dst = {hi16(lo), hi16(hi)} via single v_perm_b32 (round-20 win).
__device__ inline unsigned pkhi(float lo, float hi) {
    return __builtin_amdgcn_perm(__builtin_bit_cast(unsigned, hi),
                                 __builtin_bit_cast(unsigned, lo), 0x07060302u);
}
__device__ inline float exp2_fast(float x) {
    float r;
    asm("v_exp_f32 %0, %1" : "=v"(r) : "v"(x));
    return r;
}

#define QSCALE 0.1803368801111244f  /* 0.125 * log2(e) */

// ------- fused projection + V-transpose: grid (64, 12) x 256 threads -----------------
// (round-21/24 verified front, unchanged)
__global__ __launch_bounds__(256) void gemm_qk(const float* __restrict__ x,
                                               const float* __restrict__ Wq,
                                               const float* __restrict__ Wk,
                                               unsigned short* __restrict__ Qb,
                                               unsigned short* __restrict__ Kb,
                                               unsigned short* __restrict__ Vt) {
    __shared__ __align__(16) unsigned short sA[128 * 40];
    __shared__ __align__(16) unsigned short sB[128 * 40];
    const int tid  = threadIdx.x;
    const int by = blockIdx.y;

    if (by >= 8) {  // ---- V transpose slice ----
        const int q = by - 8;
        const int nl = tid & 127, hh = tid >> 7;
        const int h = q * 2 + hh;
        const int g = blockIdx.x * 128 + nl;       // global row 0..8191
        const int b = g >> 11, n = g & 2047;
        const int np = (n & ~15) | (n & 3) | ((n & 4) << 1) | ((n & 8) >> 1);
        const size_t xrow = ((size_t)b * 2048 + n) * 512 + h * 64;
        const size_t vbase = ((size_t)(b * 8 + h) * 64) * 2048 + np;
#pragma unroll
        for (int d0 = 0; d0 < 64; d0 += 4) {
            float4 v = *reinterpret_cast<const float4*>(&x[xrow + d0]);
            Vt[vbase + (size_t)(d0 + 0) * 2048] = f2bf(v.x);
            Vt[vbase + (size_t)(d0 + 1) * 2048] = f2bf(v.y);
            Vt[vbase + (size_t)(d0 + 2) * 2048] = f2bf(v.z);
            Vt[vbase + (size_t)(d0 + 3) * 2048] = f2bf(v.w);
        }
        return;
    }

    const int lane = tid & 63;
    const int wave = tid >> 6;
    const int wr = wave >> 1, wc = wave & 1;
    const int bm = blockIdx.x * 128;
    const float* __restrict__ Bsrc = (by < 4) ? Wq : Wk;
    unsigned short* __restrict__ C = (by < 4) ? Qb : Kb;
    const int bn = (by & 3) * 128;
    const float scale = (by < 4) ? QSCALE : 1.0f;
    const int tr = tid >> 1, th = (tid & 1) * 16;
    const int rl = lane & 15;
    const int kq = (lane >> 4) * 8;

    f32x4 acc[4][4];
#pragma unroll
    for (int m = 0; m < 4; ++m)
#pragma unroll
        for (int n = 0; n < 4; ++n) acc[m][n] = (f32x4){0.f, 0.f, 0.f, 0.f};

    for (int k0 = 0; k0 < 512; k0 += 32) {
        const float* ap = &x[(size_t)(bm + tr) * 512 + k0 + th];
        const float* bp = &Bsrc[(size_t)(bn + tr) * 512 + k0 + th];
        float4 a0 = *reinterpret_cast<const float4*>(ap);
        float4 a1 = *reinterpret_cast<const float4*>(ap + 4);
        float4 a2 = *reinterpret_cast<const float4*>(ap + 8);
        float4 a3 = *reinterpret_cast<const float4*>(ap + 12);
        float4 b0 = *reinterpret_cast<const float4*>(bp);
        float4 b1 = *reinterpret_cast<const float4*>(bp + 4);
        float4 b2 = *reinterpret_cast<const float4*>(bp + 8);
        float4 b3 = *reinterpret_cast<const float4*>(bp + 12);
        uint4 pa0 = {cvtpk(a0.x, a0.y), cvtpk(a0.z, a0.w), cvtpk(a1.x, a1.y), cvtpk(a1.z, a1.w)};
        uint4 pa1 = {cvtpk(a2.x, a2.y), cvtpk(a2.z, a2.w), cvtpk(a3.x, a3.y), cvtpk(a3.z, a3.w)};
        uint4 pb0 = {cvtpk(b0.x, b0.y), cvtpk(b0.z, b0.w), cvtpk(b1.x, b1.y), cvtpk(b1.z, b1.w)};
        uint4 pb1 = {cvtpk(b2.x, b2.y), cvtpk(b2.z, b2.w), cvtpk(b3.x, b3.y), cvtpk(b3.z, b3.w)};
        __syncthreads();
        *reinterpret_cast<uint4*>(&sA[tr * 40 + th])     = pa0;
        *reinterpret_cast<uint4*>(&sA[tr * 40 + th + 8]) = pa1;
        *reinterpret_cast<uint4*>(&sB[tr * 40 + th])     = pb0;
        *reinterpret_cast<uint4*>(&sB[tr * 40 + th + 8]) = pb1;
        __syncthreads();

        bf16x8 af[4], bfv[4];
#pragma unroll
        for (int m = 0; m < 4; ++m)
            af[m] = __builtin_bit_cast(bf16x8,
                *reinterpret_cast<const uint4*>(&sA[(wr * 64 + m * 16 + rl) * 40 + kq]));
#pragma unroll
        for (int n = 0; n < 4; ++n)
            bfv[n] = __builtin_bit_cast(bf16x8,
                *reinterpret_cast<const uint4*>(&sB[(wc * 64 + n * 16 + rl) * 40 + kq]));
#pragma unroll
        for (int m = 0; m < 4; ++m)
#pragma unroll
            for (int n = 0; n < 4; ++n)
                acc[m][n] = __builtin_amdgcn_mfma_f32_16x16x32_bf16(af[m], bfv[n], acc[m][n], 0, 0, 0);
    }

    const int rq = (lane >> 4) * 4;
#pragma unroll
    for (int m = 0; m < 4; ++m) {
        int r = bm + wr * 64 + m * 16 + rq;
#pragma unroll
        for (int n = 0; n < 4; ++n) {
            int c = bn + wc * 64 + n * 16 + rl;
#pragma unroll
            for (int reg = 0; reg < 4; ++reg)
                C[(size_t)(r + reg) * 512 + c] = f2bf(acc[m][n][reg] * scale);
        }
    }
}

// ---------------- fused flash attention: 8 waves (4qh x 2jp), KVBLK=128, dbuf --------
// grid: 512 flat blocks, XCD bh-affinity (xcd=flat&7 owns bh {4xcd..4xcd+3}) -> per-XCD
// K/V working set 2MB, L2-resident (round-11 fix that removes round-10's L2 thrash).
// block: 512 = 8 waves; wave: qh=w&3 (32 q), jp=w>>2 (64-j chunk of the 128-j tile).
// 1 barrier per 128-j tile (16 total; was 32) -> longer phases, more wave drift/overlap.
// LDS 73 KB x 2 blocks/CU = 146 < 160 KB; occupancy unchanged (grid caps 2 blocks/CU).
// Staging + fragment maps are round-10's correctness-verified KVBLK=128 indexing;
// sPos table (round-14) + pkhi P-pack (round-20) spliced in.
__global__ __launch_bounds__(512, 4) void attn_fwd(const unsigned short* __restrict__ Q,
                                                   const unsigned short* __restrict__ Kb,
                                                   const unsigned short* __restrict__ Vt,
                                                   const float* __restrict__ pos,
                                                   float* __restrict__ Out) {
    __shared__ __align__(16) unsigned char smem[74752];
    char* k0b = (char*)smem;                 // 16 KiB: K [128 j][64 d] swz
    char* v0b = (char*)smem + 16384;         // 16 KiB: V [64 d][128 j'] swz
    char* k1b = (char*)smem + 32768;
    char* v1b = (char*)smem + 49152;
    float* sPosT = (float*)(smem + 65536);   // 2048 f32 slopeL*pos (8 KiB)
    float* sMl   = (float*)(smem + 73728);   // 256 f32 (epilogue l merge)

    const int tid  = threadIdx.x;
    const int lane = tid & 63;
    const int w    = tid >> 6;
    const int l31  = lane & 31;
    const int hi   = lane >> 5;
    const int qh   = w & 3;
    const int jp   = w >> 2;
    // XCD-affine decode (512 blocks, bijective: 512 % 8 == 0)
    const int flat = blockIdx.x;
    const int xcd  = flat & 7;
    const int idx  = flat >> 3;              // 0..63
    const int bh   = xcd * 4 + (idx >> 4);
    const int qt   = idx & 15;
    const int b = bh >> 3, h = bh & 7;
    const int q0 = qt * 128 + qh * 32;
    const size_t rowbase = (size_t)b * 2048;
    const int hc = h * 64;
    const float slopeL = ldexpf(1.4426950408889634f, -(h + 1));  // slope * log2(e)

    // Q B-fragments: lane supplies Q[q=l31][c = ks*16 + hi*8 + e] (Q pre-scaled)
    bf16x8 qf0, qf1, qf2, qf3;
    {
        const unsigned short* qp = &Q[(rowbase + q0 + l31) * 512 + hc + hi * 8];
        qf0 = __builtin_bit_cast(bf16x8, *reinterpret_cast<const uint4*>(qp));
        qf1 = __builtin_bit_cast(bf16x8, *reinterpret_cast<const uint4*>(qp + 16));
        qf2 = __builtin_bit_cast(bf16x8, *reinterpret_cast<const uint4*>(qp + 32));
        qf3 = __builtin_bit_cast(bf16x8, *reinterpret_cast<const uint4*>(qp + 48));
    }
    const float ui = slopeL * pos[rowbase + q0 + l31];

    // one-time slopeL*pos table (512 threads x 4 = 2048)
    {
        float4 v = reinterpret_cast<const float4*>(pos + rowbase)[tid];
        reinterpret_cast<f32x4*>(sPosT)[tid] =
            (f32x4){v.x * slopeL, v.y * slopeL, v.z * slopeL, v.w * slopeL};
    }

    float lloc = 0.f;
    f32x16 o0, o1;
#pragma unroll
    for (int r = 0; r < 16; ++r) { o0[r] = 0.f; o1[r] = 0.f; }

    // staging (round-10 verified): K 4 thr/row x 32B (128 rows of 128B);
    // V 8 thr/row x 32B (64 rows of 256B). Same XOR involution write+read.
    const int srk = tid >> 2, sck = (tid & 3) * 16;
    const int wkb0 = srk * 128 + (((tid & 3) * 32) ^ ((srk & 7) << 4));
    const int wkb1 = srk * 128 + ((((tid & 3) * 32) + 16) ^ ((srk & 7) << 4));
    const int srv = tid >> 3, scv = (tid & 7) * 16;
    const int wvb0 = srv * 256 + (((tid & 7) * 32) ^ ((srv & 7) << 4));
    const int wvb1 = srv * 256 + ((((tid & 7) * 32) + 16) ^ ((srv & 7) << 4));
    const int kswz = (l31 & 7) << 4;                // compute-side swizzle key

    uint4 ck0, ck1, cv0, cv1;

    auto stage = [&](int j0v) {
        const unsigned short* kp = &Kb[(rowbase + j0v + srk) * 512 + hc + sck];
        const unsigned short* vp = &Vt[((size_t)bh * 64 + srv) * 2048 + j0v + scv];
        ck0 = *reinterpret_cast<const uint4*>(kp);
        ck1 = *reinterpret_cast<const uint4*>(kp + 8);
        cv0 = *reinterpret_cast<const uint4*>(vp);
        cv1 = *reinterpret_cast<const uint4*>(vp + 8);
    };
    auto writeb = [&](char* KB, char* VB) {
        *reinterpret_cast<uint4*>(KB + wkb0) = ck0;
        *reinterpret_cast<uint4*>(KB + wkb1) = ck1;
        *reinterpret_cast<uint4*>(VB + wvb0) = cv0;
        *reinterpret_cast<uint4*>(VB + wvb1) = cv1;
    };
    auto compute = [&](const char* KB, const char* VB, int j0) {
        const char* kr0 = KB + (64 * jp + l31) * 128;
        const char* kr1 = kr0 + 32 * 128;
        // ---- S chunk (64j x 32q) for this wave's (qh, jp) ----
        f32x16 s0, s1;
#pragma unroll
        for (int r = 0; r < 16; ++r) { s0[r] = 0.f; s1[r] = 0.f; }
        __builtin_amdgcn_s_setprio(1);
#pragma unroll
        for (int ks = 0; ks < 4; ++ks) {
            const int off = (ks * 32 + hi * 16) ^ kswz;
            bf16x8 kf0 = __builtin_bit_cast(bf16x8, *reinterpret_cast<const uint4*>(kr0 + off));
            bf16x8 kf1 = __builtin_bit_cast(bf16x8, *reinterpret_cast<const uint4*>(kr1 + off));
            bf16x8 qq = (ks == 0) ? qf0 : (ks == 1) ? qf1 : (ks == 2) ? qf2 : qf3;
            s0 = __builtin_amdgcn_mfma_f32_32x32x16_bf16(kf0, qq, s0, 0, 0, 0);
            s1 = __builtin_amdgcn_mfma_f32_32x32x16_bf16(kf1, qq, s1, 0, 0, 0);
        }
        __builtin_amdgcn_s_setprio(0);

        // ---- bias + exp2 (fixed reference, log2 domain) ----
        float ls = 0.f;
#pragma unroll
        for (int t = 0; t < 4; ++t) {
            f32x4 u0 = *reinterpret_cast<const f32x4*>(&sPosT[j0 + 64 * jp + 8 * t + 4 * hi]);
            f32x4 u1 = *reinterpret_cast<const f32x4*>(&sPosT[j0 + 64 * jp + 32 + 8 * t + 4 * hi]);
#pragma unroll
            for (int r = 0; r < 4; ++r) {
                float p0 = exp2_fast(s0[4 * t + r] - fabsf(u0[r] - ui));
                float p1 = exp2_fast(s1[4 * t + r] - fabsf(u1[r] - ui));
                s0[4 * t + r] = p0;
                s1[4 * t + r] = p1;
                ls += p0 + p1;
            }
        }
        lloc += ls;

        // ---- lane-local P fragments via pkhi (j = 16ks + 4hi + (e&3) + 8*(e>>2)) ----
        bf16x8 pf0 = __builtin_bit_cast(bf16x8, (uint4){
            pkhi(s0[0], s0[1]),  pkhi(s0[2], s0[3]),   pkhi(s0[4], s0[5]),   pkhi(s0[6], s0[7])});
        bf16x8 pf1 = __builtin_bit_cast(bf16x8, (uint4){
            pkhi(s0[8], s0[9]),  pkhi(s0[10], s0[11]), pkhi(s0[12], s0[13]), pkhi(s0[14], s0[15])});
        bf16x8 pf2 = __builtin_bit_cast(bf16x8, (uint4){
            pkhi(s1[0], s1[1]),  pkhi(s1[2], s1[3]),   pkhi(s1[4], s1[5]),   pkhi(s1[6], s1[7])});
        bf16x8 pf3 = __builtin_bit_cast(bf16x8, (uint4){
            pkhi(s1[8], s1[9]),  pkhi(s1[10], s1[11]), pkhi(s1[12], s1[13]), pkhi(s1[14], s1[15])});

        // ---- PV: O^T[d][q] += V-frag x P-frag; V pre-permuted -> single b128/frag ----
        const char* vr0 = VB + l31 * 256;
        const char* vr1 = VB + (32 + l31) * 256;
        __builtin_amdgcn_s_setprio(1);
#pragma unroll
        for (int ks = 0; ks < 4; ++ks) {
            const int cb = (jp * 128 + ks * 32 + hi * 16) ^ kswz;
            bf16x8 v0 = __builtin_bit_cast(bf16x8, *reinterpret_cast<const uint4*>(vr0 + cb));
            bf16x8 v1 = __builtin_bit_cast(bf16x8, *reinterpret_cast<const uint4*>(vr1 + cb));
            bf16x8 pf = (ks == 0) ? pf0 : (ks == 1) ? pf1 : (ks == 2) ? pf2 : pf3;
            o0 = __builtin_amdgcn_mfma_f32_32x32x16_bf16(v0, pf, o0, 0, 0, 0);
            o1 = __builtin_amdgcn_mfma_f32_32x32x16_bf16(v1, pf, o1, 0, 0, 0);
        }
        __builtin_amdgcn_s_setprio(0);
    };

    // prologue: tile-pair 0 -> buf0; tile-pair 1 -> regs
    stage(0);
    writeb(k0b, v0b);
    stage(128);
    __syncthreads();

    for (int t = 0; t < 16; t += 2) {
        // even iter: compute buf0, regs hold pair t+1 -> buf1
        writeb(k1b, v1b);
        if (t + 2 < 16) stage((t + 2) * 128);
        compute(k0b, v0b, t * 128);
        __syncthreads();
        // odd iter: compute buf1, regs hold pair t+2 -> buf0
        if (t + 2 < 16) {
            writeb(k0b, v0b);
            if (t + 3 < 16) stage((t + 3) * 128);
        }
        compute(k1b, v1b, (t + 1) * 128);
        __syncthreads();
    }

    // ---- epilogue: merge jp partials via LDS, normalize, direct 16B stores ----
    float lt = lloc + __shfl_xor(lloc, 32, 64);  // combine hi halves (same q)
    float* sM = (float*)smem;                    // aliases KV buffers (loop done)
    const int key = (lane & 7) << 2;
    if (jp == 1) {
        float* dst = sM + qh * 2048 + lane * 32;
#pragma unroll
        for (int i = 0; i < 4; ++i) {
            f32x4 t0 = {o0[4 * i], o0[4 * i + 1], o0[4 * i + 2], o0[4 * i + 3]};
            f32x4 t1 = {o1[4 * i], o1[4 * i + 1], o1[4 * i + 2], o1[4 * i + 3]};
            *reinterpret_cast<f32x4*>(dst + ((4 * i) ^ key))      = t0;
            *reinterpret_cast<f32x4*>(dst + ((16 + 4 * i) ^ key)) = t1;
        }
        sMl[qh * 64 + lane] = lt;
    }
    __syncthreads();
    if (jp == 0) {
        const float* src = sM + qh * 2048 + lane * 32;
#pragma unroll
        for (int i = 0; i < 4; ++i) {
            f32x4 t0 = *reinterpret_cast<const f32x4*>(src + ((4 * i) ^ key));
            f32x4 t1 = *reinterpret_cast<const f32x4*>(src + ((16 + 4 * i) ^ key));
#pragma unroll
            for (int r = 0; r < 4; ++r) { o0[4 * i + r] += t0[r]; o1[4 * i + r] += t1[r]; }
        }
        const float linv = 1.0f / (lt + sMl[qh * 64 + lane]);
        float* orow = &Out[(rowbase + q0 + l31) * 512 + hc];
#pragma unroll
        for (int t = 0; t < 4; ++t) {
            f32x4 a, c;
#pragma unroll
            for (int r = 0; r < 4; ++r) {
                a[r] = o0[4 * t + r] * linv;
                c[r] = o1[4 * t + r] * linv;
            }
            *reinterpret_cast<f32x4*>(orow + 8 * t + 4 * hi)      = a;
            *reinterpret_cast<f32x4*>(orow + 32 + 8 * t + 4 * hi) = c;
        }
    }
}

extern "C" void kernel_launch(void* const* d_in, const int* in_sizes, int n_in,
                              void* d_out, int out_size, void* d_ws, size_t ws_size,
                              hipStream_t stream) {
    const float* x   = (const float*)d_in[0];
    const float* pos = (const float*)d_in[1];
    const float* Wq  = (const float*)d_in[2];
    const float* Wk  = (const float*)d_in[3];
    float* out = (float*)d_out;

    // ws (bf16 elems): Q 4.19M | K 4.19M | Vt 4.19M  (~25MB)
    unsigned short* Qb  = (unsigned short*)d_ws;
    unsigned short* Kbf = Qb  + 4194304;
    unsigned short* Vtb = Kbf + 4194304;

    gemm_qk<<<dim3(64, 12), dim3(256), 0, stream>>>(x, Wq, Wk, Qb, Kbf, Vtb);
    attn_fwd<<<dim3(512), dim3(512), 0, stream>>>(Qb, Kbf, Vtb, pos, out);
}